// Round 6
// baseline (140.327 us; speedup 1.0000x reference)
//
#include <hip/hip_runtime.h>
#include <cmath>

// Problem constants (LowRankExperts)
constexpr int kE = 16;
constexpr int kB = 1024;
constexpr int kI = 512;
constexpr int kH = 16;
constexpr int kF = 8192;           // I*R + R*O
constexpr int kAH = 4096;          // I*R (first half of f -> A)
constexpr long long kATOT = (long long)kE * kB * kAH;  // 67108864 floats in A

typedef float f32x4 __attribute__((ext_vector_type(4)));

// ---------------------------------------------------------------------------
// Kernel A: h[e*B+b][hh] = tanh(dot(x[b,:], W1[e,:,hh]) + b1[e][hh])
// grid: (B/16, E), block: 256 = 16 b-rows x 16 hh
// ---------------------------------------------------------------------------
__global__ __launch_bounds__(256) void k_hidden(const float* __restrict__ x,
                                                const float* __restrict__ W1,
                                                const float* __restrict__ b1,
                                                float* __restrict__ hws) {
  __shared__ float xs[16][520];
  const int e  = blockIdx.y;
  const int b0 = blockIdx.x * 16;
  const int tid = threadIdx.x;

  const float4* xg = (const float4*)(x + (size_t)b0 * kI);
#pragma unroll
  for (int k = 0; k < 8; ++k) {
    int idx = tid + k * 256;            // float4 index 0..2047
    float4 v = xg[idx];
    int row = idx >> 7;                 // 128 float4 per row
    int col = (idx & 127) << 2;
    *(float4*)&xs[row][col] = v;
  }
  __syncthreads();

  const int hh = tid & 15;
  const int bl = tid >> 4;
  const float* w1e = W1 + (size_t)e * kI * kH + hh;

  float acc = 0.f;
#pragma unroll 8
  for (int i = 0; i < kI; ++i) {
    acc = fmaf(xs[bl][i], w1e[i * kH], acc);
  }
  acc += b1[e * kH + hh];
  hws[(size_t)(e * kB + b0 + bl) * kH + hh] = tanhf(acc);
}

// ---------------------------------------------------------------------------
// Kernel B v3: block = (e, region, 16 b-rows) covering the FULL 4096-col
// region width. Per row rr the block writes one complete 16KB output row;
// rows are consecutive -> each block's store stream is one 256KB strictly
// sequential region (A rows or Bf rows). Thread t owns cols t*4 and
// 2048+t*4 (two 1KB-contiguous wave-runs per row); 32 W2 float4 slices in
// registers (128 VGPR).
// XCD-bijective decode: each XCD owns 2 experts x both regions, btile
// fastest -> W2 L2 footprint ~1MB/XCD; nt-stores keep the write stream from
// evicting it.
// grid: 2048 = 8 xcd * 4 (e,region) pairs * 64 btiles; block: 512.
// ---------------------------------------------------------------------------
__global__ __launch_bounds__(512) void k_factors(const float* __restrict__ hws,
                                                 const float* __restrict__ W2,
                                                 const float* __restrict__ b2,
                                                 float* __restrict__ out) {
  __shared__ float hs[16 * kH];  // 16 rows x 16 h = 1 KB
  const int n      = blockIdx.x;
  const int xcd    = n & 7;          // HW round-robin XCD assignment
  const int local  = n >> 3;         // 0..255 within this XCD, issue order
  const int q      = local >> 6;     // 0..3 (e,region) pair for this XCD
  const int btile  = local & 63;     // fastest: sweep b within a pair
  const int e      = xcd * 2 + (q >> 1);
  const int region = q & 1;          // 0 = A half, 1 = Bf half
  const int b0     = btile * 16;
  const int tid    = threadIdx.x;

  // Stage h rows for this b-tile: 256 contiguous floats.
  if (tid < 64) {
    ((float4*)hs)[tid] = ((const float4*)(hws + (size_t)(e * kB + b0) * kH))[tid];
  }
  __syncthreads();

  const int jA = tid * 4;            // col within the 4096-wide region
  const int jB = 2048 + tid * 4;

  // W2 column slices: 2 x 16 float4, register-resident (L2-served).
  const float* w2e = W2 + (size_t)e * kH * kF + region * kAH;
  float4 wA[kH], wB[kH];
#pragma unroll
  for (int hh = 0; hh < kH; ++hh) {
    wA[hh] = *(const float4*)(w2e + (size_t)hh * kF + jA);
    wB[hh] = *(const float4*)(w2e + (size_t)hh * kF + jB);
  }
  const float4 biasA = *(const float4*)(b2 + (size_t)e * kF + region * kAH + jA);
  const float4 biasB = *(const float4*)(b2 + (size_t)e * kF + region * kAH + jB);

  float* dst = out + (size_t)region * (size_t)kATOT
                   + (size_t)(e * kB + b0) * (size_t)kAH;

#pragma unroll 4
  for (int rr = 0; rr < 16; ++rr) {
    const float4 h0 = *(const float4*)(hs + rr * kH + 0);
    const float4 h1 = *(const float4*)(hs + rr * kH + 4);
    const float4 h2 = *(const float4*)(hs + rr * kH + 8);
    const float4 h3 = *(const float4*)(hs + rr * kH + 12);
    float4 accA = biasA;
    float4 accB = biasB;
#define FMA4(hv, idx)                                     \
    accA.x = fmaf(hv, wA[idx].x, accA.x);                 \
    accA.y = fmaf(hv, wA[idx].y, accA.y);                 \
    accA.z = fmaf(hv, wA[idx].z, accA.z);                 \
    accA.w = fmaf(hv, wA[idx].w, accA.w);                 \
    accB.x = fmaf(hv, wB[idx].x, accB.x);                 \
    accB.y = fmaf(hv, wB[idx].y, accB.y);                 \
    accB.z = fmaf(hv, wB[idx].z, accB.z);                 \
    accB.w = fmaf(hv, wB[idx].w, accB.w);
    FMA4(h0.x, 0)  FMA4(h0.y, 1)  FMA4(h0.z, 2)  FMA4(h0.w, 3)
    FMA4(h1.x, 4)  FMA4(h1.y, 5)  FMA4(h1.z, 6)  FMA4(h1.w, 7)
    FMA4(h2.x, 8)  FMA4(h2.y, 9)  FMA4(h2.z, 10) FMA4(h2.w, 11)
    FMA4(h3.x, 12) FMA4(h3.y, 13) FMA4(h3.z, 14) FMA4(h3.w, 15)
#undef FMA4
    f32x4 vA; vA.x = accA.x; vA.y = accA.y; vA.z = accA.z; vA.w = accA.w;
    f32x4 vB; vB.x = accB.x; vB.y = accB.y; vB.z = accB.z; vB.w = accB.w;
    __builtin_nontemporal_store(vA, (f32x4*)(dst + (size_t)rr * (size_t)kAH + jA));
    __builtin_nontemporal_store(vB, (f32x4*)(dst + (size_t)rr * (size_t)kAH + jB));
  }
}

extern "C" void kernel_launch(void* const* d_in, const int* in_sizes, int n_in,
                              void* d_out, int out_size, void* d_ws, size_t ws_size,
                              hipStream_t stream) {
  const float* x  = (const float*)d_in[0];
  const float* W1 = (const float*)d_in[1];
  const float* b1 = (const float*)d_in[2];
  const float* W2 = (const float*)d_in[3];
  const float* b2 = (const float*)d_in[4];
  float* out = (float*)d_out;
  float* hws = (float*)d_ws;  // E*B*H floats = 1 MB

  k_hidden<<<dim3(kB / 16, kE), 256, 0, stream>>>(x, W1, b1, hws);
  k_factors<<<dim3(2048), 512, 0, stream>>>(hws, W2, b2, out);
}